// Round 5
// baseline (623.127 us; speedup 1.0000x reference)
//
#include <hip/hip_runtime.h>
#include <hip/hip_bf16.h>
#include <cstdint>
#include <cstddef>

// SNN: B=16384, D_IN=512, H0=1024, H1=512, T=8
// out[i] = b3 + (1/8) * sum_n w3[n] * popcount(spk2_pattern[i][n])
//
// NUMERICS FROZEN at the round-3 passing configuration (absmax 3.23e-3):
//  - K1: f32 VALU GEMM, per-element fmaf chain in strict k=0..511 order
//        (bit-identical spike patterns to rounds 1/3). Re-tiled 128x64,
//        8x4 per thread, 3 blocks/CU — structure only, same arithmetic.
//  - K2: MFMA, A = spike bits -> bf16 {0,1} via v_perm, B = w2 pre-split
//        hi/mid/lo bf16 (same split math as round 3, done once in d_ws),
//        3 MFMAs/frag in hi,mid,lo order — bit-identical acc values.
// The absmax gate is a spike-flip lottery (threshold < max|w3|/8): any
// numeric deviation re-rolls the dice. Do not touch arithmetic or order.

#define NB 16384
#define DIN 512
#define NH0 1024
#define NH1 512

typedef float f32x4 __attribute__((ext_vector_type(4)));
typedef short bf16x8 __attribute__((ext_vector_type(8)));

// d_ws layout (bytes)
#define WS_PAT   0u
#define WS_W2H   19922944u
#define WS_W2M   20971520u
#define WS_W2L   22020096u

__device__ inline uint16_t f2bf(float f) {
    __hip_bfloat16 h = __float2bfloat16(f);
    return *reinterpret_cast<uint16_t*>(&h);
}
__device__ inline float bf2f(uint16_t u) {
    __hip_bfloat16 h = *reinterpret_cast<__hip_bfloat16*>(&u);
    return __bfloat162float(h);
}

__global__ void init_out_kernel(float* __restrict__ out,
                                const float* __restrict__ b3, int n) {
    int i = blockIdx.x * blockDim.x + threadIdx.x;
    if (i < n) out[i] = b3[0];
}

// ---------------- split3: f32 -> bf16 hi/mid/lo (elementwise) ----------------
__global__ __launch_bounds__(256) void split3_kernel(
    const float* __restrict__ src, uint16_t* __restrict__ h,
    uint16_t* __restrict__ m, uint16_t* __restrict__ l, int n)
{
    int i = (blockIdx.x * 256 + threadIdx.x) * 4;
    if (i >= n) return;
    float4 f = *(const float4*)(src + i);
    float fv[4] = {f.x, f.y, f.z, f.w};
    uint32_t hw[2], mw[2], lw[2];
    #pragma unroll
    for (int g = 0; g < 2; ++g) {
        uint16_t hh[2], mm[2], ll[2];
        #pragma unroll
        for (int e = 0; e < 2; ++e) {
            float a = fv[2 * g + e];
            uint16_t h0 = f2bf(a);
            float d = __fsub_rn(a, bf2f(h0));
            uint16_t m0 = f2bf(d);
            float e2 = __fsub_rn(d, bf2f(m0));
            uint16_t l0 = f2bf(e2);
            hh[e] = h0; mm[e] = m0; ll[e] = l0;
        }
        hw[g] = (uint32_t)hh[0] | ((uint32_t)hh[1] << 16);
        mw[g] = (uint32_t)mm[0] | ((uint32_t)mm[1] << 16);
        lw[g] = (uint32_t)ll[0] | ((uint32_t)ll[1] << 16);
    }
    *(uint2*)(h + i) = make_uint2(hw[0], hw[1]);
    *(uint2*)(m + i) = make_uint2(mw[0], mw[1]);
    *(uint2*)(l + i) = make_uint2(lw[0], lw[1]);
}

// ------- K1: f32 VALU GEMM1 + LIF1, 128x64 tile, 8x4/thread, bit-exact ------
__global__ __launch_bounds__(256, 3) void gemm1_spike_kernel(
    const float* __restrict__ data, const float* __restrict__ w1,
    const float* __restrict__ b1, uint8_t* __restrict__ pat)
{
    __shared__ float As[128][68];   // 34.8 KB
    __shared__ float Bs[64][68];    // 17.4 KB  -> 52.2 KB total, 3 blocks/CU
    const int tid = threadIdx.x;
    const int tx = tid & 15, ty = tid >> 4;
    const int i0 = blockIdx.x * 128, n0 = blockIdx.y * 64;

    float acc[8][4] = {};

    for (int kb = 0; kb < DIN; kb += 64) {
        // stage A: 128x64 f32 (2048 float4, 8/thread)
        #pragma unroll
        for (int rep = 0; rep < 8; ++rep) {
            int idx = tid + rep * 256;
            int row = idx >> 4, c4 = (idx & 15) * 4;
            float4 va = *(const float4*)(data + (size_t)(i0 + row) * DIN + kb + c4);
            *(float4*)(&As[row][c4]) = va;
        }
        // stage B: 64x64 f32 (1024 float4, 4/thread)
        #pragma unroll
        for (int rep = 0; rep < 4; ++rep) {
            int idx = tid + rep * 256;
            int row = idx >> 4, c4 = (idx & 15) * 4;
            float4 vb = *(const float4*)(w1 + (size_t)(n0 + row) * DIN + kb + c4);
            *(float4*)(&Bs[row][c4]) = vb;
        }
        __syncthreads();
        #pragma unroll 4
        for (int k4 = 0; k4 < 16; ++k4) {
            float4 a4[8], b4[4];
            #pragma unroll
            for (int ii = 0; ii < 8; ++ii)
                a4[ii] = *(const float4*)(&As[ty + ii * 16][k4 * 4]);
            #pragma unroll
            for (int nn = 0; nn < 4; ++nn)
                b4[nn] = *(const float4*)(&Bs[tx + nn * 16][k4 * 4]);
            #pragma unroll
            for (int ii = 0; ii < 8; ++ii) {
                #pragma unroll
                for (int nn = 0; nn < 4; ++nn) {
                    acc[ii][nn] = fmaf(a4[ii].x, b4[nn].x, acc[ii][nn]);
                    acc[ii][nn] = fmaf(a4[ii].y, b4[nn].y, acc[ii][nn]);
                    acc[ii][nn] = fmaf(a4[ii].z, b4[nn].z, acc[ii][nn]);
                    acc[ii][nn] = fmaf(a4[ii].w, b4[nn].w, acc[ii][nn]);
                }
            }
        }
        __syncthreads();
    }

    // LIF1: beta=1.0; reset on OLD mem (bit-identical to round 1)
    #pragma unroll
    for (int ii = 0; ii < 8; ++ii) {
        int i = i0 + ty + ii * 16;
        #pragma unroll
        for (int nn = 0; nn < 4; ++nn) {
            int n = n0 + tx + nn * 16;
            float x = __fadd_rn(acc[ii][nn], b1[n]);
            float mem = 0.0f;
            unsigned p = 0;
            #pragma unroll
            for (int t = 0; t < 8; ++t) {
                bool reset = mem > 1.0f;
                float tmp = __fadd_rn(mem, x);
                mem = reset ? __fsub_rn(tmp, 1.0f) : tmp;
                p |= (mem > 1.0f ? 1u : 0u) << t;
            }
            pat[(size_t)i * NH0 + n] = (uint8_t)p;
        }
    }
}

// ------ K2: MFMA 8x GEMM (binary A from global, pre-split B) + LIF2 --------
__global__ __launch_bounds__(256, 2) void gemm2_mfma_kernel(
    const uint8_t* __restrict__ pat,
    const uint16_t* __restrict__ w2h, const uint16_t* __restrict__ w2m,
    const uint16_t* __restrict__ w2l,
    const float* __restrict__ b2, const float* __restrict__ w3,
    float* __restrict__ out)
{
    __shared__ __align__(16) uint16_t Bhi[64][72];
    __shared__ __align__(16) uint16_t Bmd[64][72];
    __shared__ __align__(16) uint16_t Blo[64][72];

    const int tid  = threadIdx.x;
    const int lane = tid & 63;
    const int wv   = tid >> 6;
    const int lr   = lane & 15;
    const int lg   = lane >> 4;
    const int i0   = blockIdx.x * 64, n0 = blockIdx.y * 64;

    f32x4 acc[8][4];
    #pragma unroll
    for (int t = 0; t < 8; ++t)
        #pragma unroll
        for (int nf = 0; nf < 4; ++nf)
            acc[t][nf] = (f32x4)(0.0f);

    const int srow = tid >> 2;
    const int scol = (tid & 3) * 16;
    const uint8_t* prow = pat + (size_t)(i0 + wv * 16 + lr) * NH0;

    for (int kb = 0; kb < NH0; kb += 64) {
        __syncthreads();
        const uint16_t* s1 = w2h + (size_t)(n0 + srow) * NH0 + kb + scol;
        const uint16_t* s2 = w2m + (size_t)(n0 + srow) * NH0 + kb + scol;
        const uint16_t* s3 = w2l + (size_t)(n0 + srow) * NH0 + kb + scol;
        *(uint4*)(&Bhi[srow][scol])     = *(const uint4*)(s1);
        *(uint4*)(&Bhi[srow][scol + 8]) = *(const uint4*)(s1 + 8);
        *(uint4*)(&Bmd[srow][scol])     = *(const uint4*)(s2);
        *(uint4*)(&Bmd[srow][scol + 8]) = *(const uint4*)(s2 + 8);
        *(uint4*)(&Blo[srow][scol])     = *(const uint4*)(s3);
        *(uint4*)(&Blo[srow][scol + 8]) = *(const uint4*)(s3 + 8);
        __syncthreads();

        #pragma unroll
        for (int s = 0; s < 2; ++s) {
            const int k0 = s * 32;
            bf16x8 bh[4], bm[4], bl[4];
            #pragma unroll
            for (int nf = 0; nf < 4; ++nf) {
                const int col = nf * 16 + lr;
                bh[nf] = *(const bf16x8*)(&Bhi[col][k0 + lg * 8]);
                bm[nf] = *(const bf16x8*)(&Bmd[col][k0 + lg * 8]);
                bl[nf] = *(const bf16x8*)(&Blo[col][k0 + lg * 8]);
            }
            const uint2 p8 = *(const uint2*)(prow + kb + k0 + lg * 8);
            #pragma unroll
            for (int t = 0; t < 8; ++t) {
                uint32_t y0 = (p8.x >> t) & 0x01010101u;
                uint32_t y1 = (p8.y >> t) & 0x01010101u;
                uint32_t s0 = __builtin_amdgcn_perm(0u, y0, 0x01010000u) | 0x02000200u;
                uint32_t s1x = __builtin_amdgcn_perm(0u, y0, 0x03030202u) | 0x02000200u;
                uint32_t s2x = __builtin_amdgcn_perm(0u, y1, 0x01010000u) | 0x02000200u;
                uint32_t s3x = __builtin_amdgcn_perm(0u, y1, 0x03030202u) | 0x02000200u;
                union { uint4 u; bf16x8 v; } af;
                af.u = make_uint4(__builtin_amdgcn_perm(0u, 0x3F008000u, s0),
                                  __builtin_amdgcn_perm(0u, 0x3F008000u, s1x),
                                  __builtin_amdgcn_perm(0u, 0x3F008000u, s2x),
                                  __builtin_amdgcn_perm(0u, 0x3F008000u, s3x));
                #pragma unroll
                for (int nf = 0; nf < 4; ++nf) {
                    acc[t][nf] = __builtin_amdgcn_mfma_f32_16x16x32_bf16(
                        af.v, bh[nf], acc[t][nf], 0, 0, 0);
                    acc[t][nf] = __builtin_amdgcn_mfma_f32_16x16x32_bf16(
                        af.v, bm[nf], acc[t][nf], 0, 0, 0);
                    acc[t][nf] = __builtin_amdgcn_mfma_f32_16x16x32_bf16(
                        af.v, bl[nf], acc[t][nf], 0, 0, 0);
                }
            }
        }
    }

    // LIF2 + popcount*w3 (bit-identical to round 3)
    float rowsum[4] = {0.0f, 0.0f, 0.0f, 0.0f};
    #pragma unroll
    for (int nf = 0; nf < 4; ++nf) {
        const int n = n0 + nf * 16 + lr;
        const float b2n = b2[n];
        const float w3n = w3[n];
        #pragma unroll
        for (int r = 0; r < 4; ++r) {
            float mem = 0.0f;
            int pc = 0;
            #pragma unroll
            for (int t = 0; t < 8; ++t) {
                bool reset = mem > 1.0f;
                float x   = __fadd_rn(acc[t][nf][r], b2n);
                float tmp = __fadd_rn(__fmul_rn(0.95f, mem), x);
                mem = reset ? __fsub_rn(tmp, 1.0f) : tmp;
                pc += (mem > 1.0f) ? 1 : 0;
            }
            rowsum[r] = fmaf(w3n, (float)pc, rowsum[r]);
        }
    }
    #pragma unroll
    for (int r = 0; r < 4; ++r) {
        float s = rowsum[r];
        s += __shfl_xor(s, 1);
        s += __shfl_xor(s, 2);
        s += __shfl_xor(s, 4);
        s += __shfl_xor(s, 8);
        if (lr == 0)
            atomicAdd(&out[i0 + wv * 16 + lg * 4 + r], 0.125f * s);
    }
}

extern "C" void kernel_launch(void* const* d_in, const int* in_sizes, int n_in,
                              void* d_out, int out_size, void* d_ws, size_t ws_size,
                              hipStream_t stream) {
    const float* data = (const float*)d_in[0];
    const float* w1   = (const float*)d_in[1];
    const float* b1   = (const float*)d_in[2];
    const float* w2   = (const float*)d_in[3];
    const float* b2   = (const float*)d_in[4];
    const float* w3   = (const float*)d_in[5];
    const float* b3   = (const float*)d_in[6];
    float* out = (float*)d_out;

    char* ws = (char*)d_ws;
    uint8_t*  pat = (uint8_t*)(ws + WS_PAT);
    uint16_t* w2h = (uint16_t*)(ws + WS_W2H);
    uint16_t* w2m = (uint16_t*)(ws + WS_W2M);
    uint16_t* w2l = (uint16_t*)(ws + WS_W2L);

    init_out_kernel<<<(NB + 255) / 256, 256, 0, stream>>>(out, b3, NB);
    split3_kernel<<<(NH1 * NH0 / 4 + 255) / 256, 256, 0, stream>>>(w2, w2h, w2m, w2l, NH1 * NH0);
    gemm1_spike_kernel<<<dim3(NB / 128, NH0 / 64), 256, 0, stream>>>(data, w1, b1, pat);
    gemm2_mfma_kernel<<<dim3(NB / 64, NH1 / 64), 256, 0, stream>>>(pat, w2h, w2m, w2l, b2, w3, out);
}

// Round 6
// 617.697 us; speedup vs baseline: 1.0088x; 1.0088x over previous
//
#include <hip/hip_runtime.h>
#include <hip/hip_bf16.h>
#include <cstdint>
#include <cstddef>

// SNN: B=16384, D_IN=512, H0=1024, H1=512, T=8
// out[i] = b3 + (1/8) * sum_n w3[n] * popcount(spk2_pattern[i][n])
//
// NUMERICS FROZEN at the round-3 passing configuration (absmax 3.234863e-3):
//  - K1: f32 VALU GEMM, per-element fmaf chain in strict k=0..511 order.
//  - K2: MFMA, A = spike bits -> bf16 {0,1} via v_perm, B = w2 pre-split
//        hi/mid/lo bf16, 3 MFMAs/frag in hi,mid,lo order, s->t->nf loop order.
// The absmax gate is a spike-flip lottery (threshold < max|w3|/8): any
// numeric deviation re-rolls the dice. Structure-only changes allowed.
//
// Round 6 structure changes (bit-exact):
//  - pat stored BLOCKED: pat2[k>>6][i][k&63] -> K2's 64x64 A-tile is one
//    contiguous 4KB block (perfectly coalesced stage), K1 writes land in
//    64B lines (round-5's unstaged reads caused FETCH 51MB / WRITE 60MB
//    cross-XCD writeback storm; this kills it at the layout level).
//  - K2: Ap LDS staging restored (round-3 indexing) + pre-split w2 kept.
//  - K1: 128x128 tile, 8x8/thread (intensity 2.67 -> 4 FMA/LDS-float).

#define NB 16384
#define DIN 512
#define NH0 1024
#define NH1 512

typedef float f32x4 __attribute__((ext_vector_type(4)));
typedef short bf16x8 __attribute__((ext_vector_type(8)));

// d_ws layout (bytes)
#define WS_PAT   0u
#define WS_W2H   19922944u
#define WS_W2M   20971520u
#define WS_W2L   22020096u

__device__ inline uint16_t f2bf(float f) {
    __hip_bfloat16 h = __float2bfloat16(f);
    return *reinterpret_cast<uint16_t*>(&h);
}
__device__ inline float bf2f(uint16_t u) {
    __hip_bfloat16 h = *reinterpret_cast<__hip_bfloat16*>(&u);
    return __bfloat162float(h);
}

__global__ void init_out_kernel(float* __restrict__ out,
                                const float* __restrict__ b3, int n) {
    int i = blockIdx.x * blockDim.x + threadIdx.x;
    if (i < n) out[i] = b3[0];
}

// ---------------- split3: f32 -> bf16 hi/mid/lo (elementwise) ----------------
__global__ __launch_bounds__(256) void split3_kernel(
    const float* __restrict__ src, uint16_t* __restrict__ h,
    uint16_t* __restrict__ m, uint16_t* __restrict__ l, int n)
{
    int i = (blockIdx.x * 256 + threadIdx.x) * 4;
    if (i >= n) return;
    float4 f = *(const float4*)(src + i);
    float fv[4] = {f.x, f.y, f.z, f.w};
    uint32_t hw[2], mw[2], lw[2];
    #pragma unroll
    for (int g = 0; g < 2; ++g) {
        uint16_t hh[2], mm[2], ll[2];
        #pragma unroll
        for (int e = 0; e < 2; ++e) {
            float a = fv[2 * g + e];
            uint16_t h0 = f2bf(a);
            float d = __fsub_rn(a, bf2f(h0));
            uint16_t m0 = f2bf(d);
            float e2 = __fsub_rn(d, bf2f(m0));
            uint16_t l0 = f2bf(e2);
            hh[e] = h0; mm[e] = m0; ll[e] = l0;
        }
        hw[g] = (uint32_t)hh[0] | ((uint32_t)hh[1] << 16);
        mw[g] = (uint32_t)mm[0] | ((uint32_t)mm[1] << 16);
        lw[g] = (uint32_t)ll[0] | ((uint32_t)ll[1] << 16);
    }
    *(uint2*)(h + i) = make_uint2(hw[0], hw[1]);
    *(uint2*)(m + i) = make_uint2(mw[0], mw[1]);
    *(uint2*)(l + i) = make_uint2(lw[0], lw[1]);
}

// --- K1: f32 VALU GEMM1 + LIF1, 128x128 tile, 8x8/thread, bit-exact chain ---
__global__ __launch_bounds__(256, 2) void gemm1_spike_kernel(
    const float* __restrict__ data, const float* __restrict__ w1,
    const float* __restrict__ b1, uint8_t* __restrict__ pat)
{
    __shared__ float As[128][68];   // 34.8 KB
    __shared__ float Bs[128][68];   // 34.8 KB -> 69.6 KB, 2 blocks/CU
    const int tid = threadIdx.x;
    const int tx = tid & 15, ty = tid >> 4;
    const int i0 = blockIdx.x * 128, n0 = blockIdx.y * 128;

    float acc[8][8] = {};

    for (int kb = 0; kb < DIN; kb += 64) {
        #pragma unroll
        for (int rep = 0; rep < 8; ++rep) {
            int idx = tid + rep * 256;
            int row = idx >> 4, c4 = (idx & 15) * 4;
            *(float4*)(&As[row][c4]) =
                *(const float4*)(data + (size_t)(i0 + row) * DIN + kb + c4);
            *(float4*)(&Bs[row][c4]) =
                *(const float4*)(w1 + (size_t)(n0 + row) * DIN + kb + c4);
        }
        __syncthreads();
        #pragma unroll 2
        for (int k4 = 0; k4 < 16; ++k4) {
            float4 a4[8], b4[8];
            #pragma unroll
            for (int ii = 0; ii < 8; ++ii)
                a4[ii] = *(const float4*)(&As[ty + ii * 16][k4 * 4]);
            #pragma unroll
            for (int nn = 0; nn < 8; ++nn)
                b4[nn] = *(const float4*)(&Bs[tx + nn * 16][k4 * 4]);
            #pragma unroll
            for (int ii = 0; ii < 8; ++ii) {
                #pragma unroll
                for (int nn = 0; nn < 8; ++nn) {
                    acc[ii][nn] = fmaf(a4[ii].x, b4[nn].x, acc[ii][nn]);
                    acc[ii][nn] = fmaf(a4[ii].y, b4[nn].y, acc[ii][nn]);
                    acc[ii][nn] = fmaf(a4[ii].z, b4[nn].z, acc[ii][nn]);
                    acc[ii][nn] = fmaf(a4[ii].w, b4[nn].w, acc[ii][nn]);
                }
            }
        }
        __syncthreads();
    }

    // LIF1 (bit-identical chain) -> blocked pat2[n>>6][i][n&63]
    #pragma unroll
    for (int ii = 0; ii < 8; ++ii) {
        const int i = i0 + ty + ii * 16;
        #pragma unroll
        for (int nn = 0; nn < 8; ++nn) {
            const int n = n0 + tx + nn * 16;
            float x = __fadd_rn(acc[ii][nn], b1[n]);
            float mem = 0.0f;
            unsigned p = 0;
            #pragma unroll
            for (int t = 0; t < 8; ++t) {
                bool reset = mem > 1.0f;
                float tmp = __fadd_rn(mem, x);
                mem = reset ? __fsub_rn(tmp, 1.0f) : tmp;
                p |= (mem > 1.0f ? 1u : 0u) << t;
            }
            pat[(size_t)(n >> 6) * (NB * 64) + (size_t)i * 64 + (n & 63)] = (uint8_t)p;
        }
    }
}

// ------ K2: MFMA 8x GEMM (binary A staged via LDS, pre-split B) + LIF2 ------
__global__ __launch_bounds__(256, 2) void gemm2_mfma_kernel(
    const uint8_t* __restrict__ pat,
    const uint16_t* __restrict__ w2h, const uint16_t* __restrict__ w2m,
    const uint16_t* __restrict__ w2l,
    const float* __restrict__ b2, const float* __restrict__ w3,
    float* __restrict__ out)
{
    __shared__ __align__(16) uint16_t Bhi[64][72];
    __shared__ __align__(16) uint16_t Bmd[64][72];
    __shared__ __align__(16) uint16_t Blo[64][72];
    __shared__ __align__(16) uint8_t  Ap[64][80];

    const int tid  = threadIdx.x;
    const int lane = tid & 63;
    const int wv   = tid >> 6;
    const int lr   = lane & 15;
    const int lg   = lane >> 4;
    const int i0   = blockIdx.x * 64, n0 = blockIdx.y * 64;

    f32x4 acc[8][4];
    #pragma unroll
    for (int t = 0; t < 8; ++t)
        #pragma unroll
        for (int nf = 0; nf < 4; ++nf)
            acc[t][nf] = (f32x4)(0.0f);

    const int srow = tid >> 2;
    const int scol = (tid & 3) * 16;

    for (int kb = 0; kb < NH0; kb += 64) {
        __syncthreads();
        const uint16_t* s1 = w2h + (size_t)(n0 + srow) * NH0 + kb + scol;
        const uint16_t* s2 = w2m + (size_t)(n0 + srow) * NH0 + kb + scol;
        const uint16_t* s3 = w2l + (size_t)(n0 + srow) * NH0 + kb + scol;
        *(uint4*)(&Bhi[srow][scol])     = *(const uint4*)(s1);
        *(uint4*)(&Bhi[srow][scol + 8]) = *(const uint4*)(s1 + 8);
        *(uint4*)(&Bmd[srow][scol])     = *(const uint4*)(s2);
        *(uint4*)(&Bmd[srow][scol + 8]) = *(const uint4*)(s2 + 8);
        *(uint4*)(&Blo[srow][scol])     = *(const uint4*)(s3);
        *(uint4*)(&Blo[srow][scol + 8]) = *(const uint4*)(s3 + 8);
        // pattern tile: one contiguous 4KB block, one uint4 per thread
        {
            const uint8_t* psrc = pat + (size_t)(kb >> 6) * (NB * 64) + (size_t)i0 * 64;
            uint4 pv = *(const uint4*)(psrc + tid * 16);
            *(uint4*)(&Ap[srow][scol]) = pv;
        }
        __syncthreads();

        #pragma unroll
        for (int s = 0; s < 2; ++s) {
            const int k0 = s * 32;
            bf16x8 bh[4], bm[4], bl[4];
            #pragma unroll
            for (int nf = 0; nf < 4; ++nf) {
                const int col = nf * 16 + lr;
                bh[nf] = *(const bf16x8*)(&Bhi[col][k0 + lg * 8]);
                bm[nf] = *(const bf16x8*)(&Bmd[col][k0 + lg * 8]);
                bl[nf] = *(const bf16x8*)(&Blo[col][k0 + lg * 8]);
            }
            const uint2 p8 = *(const uint2*)(&Ap[wv * 16 + lr][k0 + lg * 8]);
            #pragma unroll
            for (int t = 0; t < 8; ++t) {
                uint32_t y0 = (p8.x >> t) & 0x01010101u;
                uint32_t y1 = (p8.y >> t) & 0x01010101u;
                uint32_t s0 = __builtin_amdgcn_perm(0u, y0, 0x01010000u) | 0x02000200u;
                uint32_t s1x = __builtin_amdgcn_perm(0u, y0, 0x03030202u) | 0x02000200u;
                uint32_t s2x = __builtin_amdgcn_perm(0u, y1, 0x01010000u) | 0x02000200u;
                uint32_t s3x = __builtin_amdgcn_perm(0u, y1, 0x03030202u) | 0x02000200u;
                union { uint4 u; bf16x8 v; } af;
                af.u = make_uint4(__builtin_amdgcn_perm(0u, 0x3F008000u, s0),
                                  __builtin_amdgcn_perm(0u, 0x3F008000u, s1x),
                                  __builtin_amdgcn_perm(0u, 0x3F008000u, s2x),
                                  __builtin_amdgcn_perm(0u, 0x3F008000u, s3x));
                #pragma unroll
                for (int nf = 0; nf < 4; ++nf) {
                    acc[t][nf] = __builtin_amdgcn_mfma_f32_16x16x32_bf16(
                        af.v, bh[nf], acc[t][nf], 0, 0, 0);
                    acc[t][nf] = __builtin_amdgcn_mfma_f32_16x16x32_bf16(
                        af.v, bm[nf], acc[t][nf], 0, 0, 0);
                    acc[t][nf] = __builtin_amdgcn_mfma_f32_16x16x32_bf16(
                        af.v, bl[nf], acc[t][nf], 0, 0, 0);
                }
            }
        }
    }

    // LIF2 + popcount*w3 (bit-identical to round 3)
    float rowsum[4] = {0.0f, 0.0f, 0.0f, 0.0f};
    #pragma unroll
    for (int nf = 0; nf < 4; ++nf) {
        const int n = n0 + nf * 16 + lr;
        const float b2n = b2[n];
        const float w3n = w3[n];
        #pragma unroll
        for (int r = 0; r < 4; ++r) {
            float mem = 0.0f;
            int pc = 0;
            #pragma unroll
            for (int t = 0; t < 8; ++t) {
                bool reset = mem > 1.0f;
                float x   = __fadd_rn(acc[t][nf][r], b2n);
                float tmp = __fadd_rn(__fmul_rn(0.95f, mem), x);
                mem = reset ? __fsub_rn(tmp, 1.0f) : tmp;
                pc += (mem > 1.0f) ? 1 : 0;
            }
            rowsum[r] = fmaf(w3n, (float)pc, rowsum[r]);
        }
    }
    #pragma unroll
    for (int r = 0; r < 4; ++r) {
        float s = rowsum[r];
        s += __shfl_xor(s, 1);
        s += __shfl_xor(s, 2);
        s += __shfl_xor(s, 4);
        s += __shfl_xor(s, 8);
        if (lr == 0)
            atomicAdd(&out[i0 + wv * 16 + lg * 4 + r], 0.125f * s);
    }
}

extern "C" void kernel_launch(void* const* d_in, const int* in_sizes, int n_in,
                              void* d_out, int out_size, void* d_ws, size_t ws_size,
                              hipStream_t stream) {
    const float* data = (const float*)d_in[0];
    const float* w1   = (const float*)d_in[1];
    const float* b1   = (const float*)d_in[2];
    const float* w2   = (const float*)d_in[3];
    const float* b2   = (const float*)d_in[4];
    const float* w3   = (const float*)d_in[5];
    const float* b3   = (const float*)d_in[6];
    float* out = (float*)d_out;

    char* ws = (char*)d_ws;
    uint8_t*  pat = (uint8_t*)(ws + WS_PAT);   // blocked [16][16384][64]
    uint16_t* w2h = (uint16_t*)(ws + WS_W2H);
    uint16_t* w2m = (uint16_t*)(ws + WS_W2M);
    uint16_t* w2l = (uint16_t*)(ws + WS_W2L);

    init_out_kernel<<<(NB + 255) / 256, 256, 0, stream>>>(out, b3, NB);
    split3_kernel<<<(NH1 * NH0 / 4 + 255) / 256, 256, 0, stream>>>(w2, w2h, w2m, w2l, NH1 * NH0);
    gemm1_spike_kernel<<<dim3(NB / 128, NH0 / 128), 256, 0, stream>>>(data, w1, b1, pat);
    gemm2_mfma_kernel<<<dim3(NB / 64, NH1 / 64), 256, 0, stream>>>(pat, w2h, w2m, w2l, b2, w3, out);
}

// Round 7
// 563.098 us; speedup vs baseline: 1.1066x; 1.0970x over previous
//
#include <hip/hip_runtime.h>
#include <hip/hip_bf16.h>
#include <cstdint>
#include <cstddef>

// SNN: B=16384, D_IN=512, H0=1024, H1=512, T=8
// out[i] = b3 + (1/8) * sum_n w3[n] * popcount(spk2_pattern[i][n])
//
// NUMERICS FROZEN at the round-3 passing configuration (absmax 3.234863e-3):
//  - K1: f32 VALU GEMM, per-element fmaf chain in strict k=0..511 order
//        (kb ascending, k4 ascending, x/y/z/w) -> spike patterns bit-exact.
//  - K2: MFMA, A = spike bits -> bf16 {0,1} via v_perm, B = w2 pre-split
//        hi/mid/lo bf16, 3 MFMAs/frag in hi,mid,lo order, s->t->nf loop order.
// The absmax gate is a spike-flip lottery (threshold < max|w3|/8): any
// numeric deviation re-rolls the dice. Structure-only changes allowed.
//
// Round 7 structure changes (bit-exact):
//  - K2: LDS double-buffer + async-stage split. Next tile's global loads are
//    issued BEFORE the MFMA block (into regs), written to the alternate LDS
//    buffer AFTER it; ONE barrier per K-step (was 2). Removes the barrier
//    drain that held MfmaUtil at 52%.
//  - K1: 512-thread blocks, 128x128 tile, 8x4/thread -> 4 waves/SIMD
//    (was 2) for latency hiding; same per-element accumulation order.

#define NB 16384
#define DIN 512
#define NH0 1024
#define NH1 512

typedef float f32x4 __attribute__((ext_vector_type(4)));
typedef short bf16x8 __attribute__((ext_vector_type(8)));

// d_ws layout (bytes)
#define WS_PAT   0u
#define WS_W2H   19922944u
#define WS_W2M   20971520u
#define WS_W2L   22020096u

__device__ inline uint16_t f2bf(float f) {
    __hip_bfloat16 h = __float2bfloat16(f);
    return *reinterpret_cast<uint16_t*>(&h);
}
__device__ inline float bf2f(uint16_t u) {
    __hip_bfloat16 h = *reinterpret_cast<__hip_bfloat16*>(&u);
    return __bfloat162float(h);
}

__global__ void init_out_kernel(float* __restrict__ out,
                                const float* __restrict__ b3, int n) {
    int i = blockIdx.x * blockDim.x + threadIdx.x;
    if (i < n) out[i] = b3[0];
}

// ---------------- split3: f32 -> bf16 hi/mid/lo (elementwise) ----------------
__global__ __launch_bounds__(256) void split3_kernel(
    const float* __restrict__ src, uint16_t* __restrict__ h,
    uint16_t* __restrict__ m, uint16_t* __restrict__ l, int n)
{
    int i = (blockIdx.x * 256 + threadIdx.x) * 4;
    if (i >= n) return;
    float4 f = *(const float4*)(src + i);
    float fv[4] = {f.x, f.y, f.z, f.w};
    uint32_t hw[2], mw[2], lw[2];
    #pragma unroll
    for (int g = 0; g < 2; ++g) {
        uint16_t hh[2], mm[2], ll[2];
        #pragma unroll
        for (int e = 0; e < 2; ++e) {
            float a = fv[2 * g + e];
            uint16_t h0 = f2bf(a);
            float d = __fsub_rn(a, bf2f(h0));
            uint16_t m0 = f2bf(d);
            float e2 = __fsub_rn(d, bf2f(m0));
            uint16_t l0 = f2bf(e2);
            hh[e] = h0; mm[e] = m0; ll[e] = l0;
        }
        hw[g] = (uint32_t)hh[0] | ((uint32_t)hh[1] << 16);
        mw[g] = (uint32_t)mm[0] | ((uint32_t)mm[1] << 16);
        lw[g] = (uint32_t)ll[0] | ((uint32_t)ll[1] << 16);
    }
    *(uint2*)(h + i) = make_uint2(hw[0], hw[1]);
    *(uint2*)(m + i) = make_uint2(mw[0], mw[1]);
    *(uint2*)(l + i) = make_uint2(lw[0], lw[1]);
}

// - K1: f32 VALU GEMM1 + LIF1, 512 thr, 128x128 tile, 8x4/thread, bit-exact -
__global__ __launch_bounds__(512, 4) void gemm1_spike_kernel(
    const float* __restrict__ data, const float* __restrict__ w1,
    const float* __restrict__ b1, uint8_t* __restrict__ pat)
{
    __shared__ float As[128][68];   // 34.8 KB
    __shared__ float Bs[128][68];   // 34.8 KB -> 69.6 KB, 2 blocks/CU (16 w/CU)
    const int tid = threadIdx.x;
    const int tx = tid & 31;        // n-position (x4 groups of 32)
    const int ty = tid >> 5;        // i-position (x8 groups of 16)
    const int i0 = blockIdx.x * 128, n0 = blockIdx.y * 128;

    float acc[8][4] = {};

    for (int kb = 0; kb < DIN; kb += 64) {
        #pragma unroll
        for (int rep = 0; rep < 4; ++rep) {
            int idx = tid + rep * 512;
            int row = idx >> 4, c4 = (idx & 15) * 4;
            *(float4*)(&As[row][c4]) =
                *(const float4*)(data + (size_t)(i0 + row) * DIN + kb + c4);
            *(float4*)(&Bs[row][c4]) =
                *(const float4*)(w1 + (size_t)(n0 + row) * DIN + kb + c4);
        }
        __syncthreads();
        #pragma unroll 2
        for (int k4 = 0; k4 < 16; ++k4) {
            float4 a4[8], b4[4];
            #pragma unroll
            for (int ii = 0; ii < 8; ++ii)
                a4[ii] = *(const float4*)(&As[ty + ii * 16][k4 * 4]);
            #pragma unroll
            for (int nn = 0; nn < 4; ++nn)
                b4[nn] = *(const float4*)(&Bs[tx + nn * 32][k4 * 4]);
            #pragma unroll
            for (int ii = 0; ii < 8; ++ii) {
                #pragma unroll
                for (int nn = 0; nn < 4; ++nn) {
                    acc[ii][nn] = fmaf(a4[ii].x, b4[nn].x, acc[ii][nn]);
                    acc[ii][nn] = fmaf(a4[ii].y, b4[nn].y, acc[ii][nn]);
                    acc[ii][nn] = fmaf(a4[ii].z, b4[nn].z, acc[ii][nn]);
                    acc[ii][nn] = fmaf(a4[ii].w, b4[nn].w, acc[ii][nn]);
                }
            }
        }
        __syncthreads();
    }

    // LIF1 (bit-identical chain) -> blocked pat2[n>>6][i][n&63]
    #pragma unroll
    for (int ii = 0; ii < 8; ++ii) {
        const int i = i0 + ty + ii * 16;
        #pragma unroll
        for (int nn = 0; nn < 4; ++nn) {
            const int n = n0 + tx + nn * 32;
            float x = __fadd_rn(acc[ii][nn], b1[n]);
            float mem = 0.0f;
            unsigned p = 0;
            #pragma unroll
            for (int t = 0; t < 8; ++t) {
                bool reset = mem > 1.0f;
                float tmp = __fadd_rn(mem, x);
                mem = reset ? __fsub_rn(tmp, 1.0f) : tmp;
                p |= (mem > 1.0f ? 1u : 0u) << t;
            }
            pat[(size_t)(n >> 6) * (NB * 64) + (size_t)i * 64 + (n & 63)] = (uint8_t)p;
        }
    }
}

// -- K2: MFMA 8x GEMM, double-buffered LDS, async-stage split, 1 barrier/step --
__global__ __launch_bounds__(256, 2) void gemm2_mfma_kernel(
    const uint8_t* __restrict__ pat,
    const uint16_t* __restrict__ w2h, const uint16_t* __restrict__ w2m,
    const uint16_t* __restrict__ w2l,
    const float* __restrict__ b2, const float* __restrict__ w3,
    float* __restrict__ out)
{
    __shared__ __align__(16) uint16_t Bhi[2][64][72];
    __shared__ __align__(16) uint16_t Bmd[2][64][72];
    __shared__ __align__(16) uint16_t Blo[2][64][72];
    __shared__ __align__(16) uint8_t  Ap[2][64][80];   // total exactly 64 KB

    const int tid  = threadIdx.x;
    const int lane = tid & 63;
    const int wv   = tid >> 6;
    const int lr   = lane & 15;
    const int lg   = lane >> 4;
    const int i0   = blockIdx.x * 64, n0 = blockIdx.y * 64;

    f32x4 acc[8][4];
    #pragma unroll
    for (int t = 0; t < 8; ++t)
        #pragma unroll
        for (int nf = 0; nf < 4; ++nf)
            acc[t][nf] = (f32x4)(0.0f);

    const int srow = tid >> 2;
    const int scol = (tid & 3) * 16;
    const size_t wbase = (size_t)(n0 + srow) * NH0 + scol;
    const size_t pbase = (size_t)i0 * 64 + (size_t)tid * 16;

    uint4 rh0, rh1, rm0, rm1, rl0, rl1, rp;

    // prologue: stage tile 0 into buffer 0
    {
        const uint16_t* s1 = w2h + wbase;
        const uint16_t* s2 = w2m + wbase;
        const uint16_t* s3 = w2l + wbase;
        rh0 = *(const uint4*)(s1); rh1 = *(const uint4*)(s1 + 8);
        rm0 = *(const uint4*)(s2); rm1 = *(const uint4*)(s2 + 8);
        rl0 = *(const uint4*)(s3); rl1 = *(const uint4*)(s3 + 8);
        rp  = *(const uint4*)(pat + pbase);
        *(uint4*)(&Bhi[0][srow][scol])     = rh0;
        *(uint4*)(&Bhi[0][srow][scol + 8]) = rh1;
        *(uint4*)(&Bmd[0][srow][scol])     = rm0;
        *(uint4*)(&Bmd[0][srow][scol + 8]) = rm1;
        *(uint4*)(&Blo[0][srow][scol])     = rl0;
        *(uint4*)(&Blo[0][srow][scol + 8]) = rl1;
        *(uint4*)(&Ap[0][srow][scol])      = rp;
    }

    int cur = 0;
    for (int kbi = 0; kbi < 16; ++kbi) {
        __syncthreads();   // buf[cur] ready; buf[cur^1] free to overwrite
        // issue next tile's global loads early (latency hides under MFMAs)
        if (kbi < 15) {
            const int kb = (kbi + 1) * 64;
            const uint16_t* s1 = w2h + wbase + kb;
            const uint16_t* s2 = w2m + wbase + kb;
            const uint16_t* s3 = w2l + wbase + kb;
            rh0 = *(const uint4*)(s1); rh1 = *(const uint4*)(s1 + 8);
            rm0 = *(const uint4*)(s2); rm1 = *(const uint4*)(s2 + 8);
            rl0 = *(const uint4*)(s3); rl1 = *(const uint4*)(s3 + 8);
            rp  = *(const uint4*)(pat + (size_t)(kbi + 1) * (NB * 64) + pbase);
        }

        // ---- compute tile kbi from buf[cur] (MFMA order frozen) ----
        #pragma unroll
        for (int s = 0; s < 2; ++s) {
            const int k0 = s * 32;
            bf16x8 bh[4], bm[4], bl[4];
            #pragma unroll
            for (int nf = 0; nf < 4; ++nf) {
                const int col = nf * 16 + lr;
                bh[nf] = *(const bf16x8*)(&Bhi[cur][col][k0 + lg * 8]);
                bm[nf] = *(const bf16x8*)(&Bmd[cur][col][k0 + lg * 8]);
                bl[nf] = *(const bf16x8*)(&Blo[cur][col][k0 + lg * 8]);
            }
            const uint2 p8 = *(const uint2*)(&Ap[cur][wv * 16 + lr][k0 + lg * 8]);
            #pragma unroll
            for (int t = 0; t < 8; ++t) {
                uint32_t y0 = (p8.x >> t) & 0x01010101u;
                uint32_t y1 = (p8.y >> t) & 0x01010101u;
                uint32_t s0 = __builtin_amdgcn_perm(0u, y0, 0x01010000u) | 0x02000200u;
                uint32_t s1x = __builtin_amdgcn_perm(0u, y0, 0x03030202u) | 0x02000200u;
                uint32_t s2x = __builtin_amdgcn_perm(0u, y1, 0x01010000u) | 0x02000200u;
                uint32_t s3x = __builtin_amdgcn_perm(0u, y1, 0x03030202u) | 0x02000200u;
                union { uint4 u; bf16x8 v; } af;
                af.u = make_uint4(__builtin_amdgcn_perm(0u, 0x3F008000u, s0),
                                  __builtin_amdgcn_perm(0u, 0x3F008000u, s1x),
                                  __builtin_amdgcn_perm(0u, 0x3F008000u, s2x),
                                  __builtin_amdgcn_perm(0u, 0x3F008000u, s3x));
                #pragma unroll
                for (int nf = 0; nf < 4; ++nf) {
                    acc[t][nf] = __builtin_amdgcn_mfma_f32_16x16x32_bf16(
                        af.v, bh[nf], acc[t][nf], 0, 0, 0);
                    acc[t][nf] = __builtin_amdgcn_mfma_f32_16x16x32_bf16(
                        af.v, bm[nf], acc[t][nf], 0, 0, 0);
                    acc[t][nf] = __builtin_amdgcn_mfma_f32_16x16x32_bf16(
                        af.v, bl[nf], acc[t][nf], 0, 0, 0);
                }
            }
        }

        // write prefetched tile into the other buffer (no barrier needed here;
        // next iteration's barrier publishes it)
        if (kbi < 15) {
            const int nb = cur ^ 1;
            *(uint4*)(&Bhi[nb][srow][scol])     = rh0;
            *(uint4*)(&Bhi[nb][srow][scol + 8]) = rh1;
            *(uint4*)(&Bmd[nb][srow][scol])     = rm0;
            *(uint4*)(&Bmd[nb][srow][scol + 8]) = rm1;
            *(uint4*)(&Blo[nb][srow][scol])     = rl0;
            *(uint4*)(&Blo[nb][srow][scol + 8]) = rl1;
            *(uint4*)(&Ap[nb][srow][scol])      = rp;
        }
        cur ^= 1;
    }

    // LIF2 + popcount*w3 (bit-identical to round 3)
    float rowsum[4] = {0.0f, 0.0f, 0.0f, 0.0f};
    #pragma unroll
    for (int nf = 0; nf < 4; ++nf) {
        const int n = n0 + nf * 16 + lr;
        const float b2n = b2[n];
        const float w3n = w3[n];
        #pragma unroll
        for (int r = 0; r < 4; ++r) {
            float mem = 0.0f;
            int pc = 0;
            #pragma unroll
            for (int t = 0; t < 8; ++t) {
                bool reset = mem > 1.0f;
                float x   = __fadd_rn(acc[t][nf][r], b2n);
                float tmp = __fadd_rn(__fmul_rn(0.95f, mem), x);
                mem = reset ? __fsub_rn(tmp, 1.0f) : tmp;
                pc += (mem > 1.0f) ? 1 : 0;
            }
            rowsum[r] = fmaf(w3n, (float)pc, rowsum[r]);
        }
    }
    #pragma unroll
    for (int r = 0; r < 4; ++r) {
        float s = rowsum[r];
        s += __shfl_xor(s, 1);
        s += __shfl_xor(s, 2);
        s += __shfl_xor(s, 4);
        s += __shfl_xor(s, 8);
        if (lr == 0)
            atomicAdd(&out[i0 + wv * 16 + lg * 4 + r], 0.125f * s);
    }
}

extern "C" void kernel_launch(void* const* d_in, const int* in_sizes, int n_in,
                              void* d_out, int out_size, void* d_ws, size_t ws_size,
                              hipStream_t stream) {
    const float* data = (const float*)d_in[0];
    const float* w1   = (const float*)d_in[1];
    const float* b1   = (const float*)d_in[2];
    const float* w2   = (const float*)d_in[3];
    const float* b2   = (const float*)d_in[4];
    const float* w3   = (const float*)d_in[5];
    const float* b3   = (const float*)d_in[6];
    float* out = (float*)d_out;

    char* ws = (char*)d_ws;
    uint8_t*  pat = (uint8_t*)(ws + WS_PAT);   // blocked [16][16384][64]
    uint16_t* w2h = (uint16_t*)(ws + WS_W2H);
    uint16_t* w2m = (uint16_t*)(ws + WS_W2M);
    uint16_t* w2l = (uint16_t*)(ws + WS_W2L);

    init_out_kernel<<<(NB + 255) / 256, 256, 0, stream>>>(out, b3, NB);
    split3_kernel<<<(NH1 * NH0 / 4 + 255) / 256, 256, 0, stream>>>(w2, w2h, w2m, w2l, NH1 * NH0);
    gemm1_spike_kernel<<<dim3(NB / 128, NH0 / 128), 512, 0, stream>>>(data, w1, b1, pat);
    gemm2_mfma_kernel<<<dim3(NB / 64, NH1 / 64), 256, 0, stream>>>(pat, w2h, w2m, w2l, b2, w3, out);
}